// Round 5
// baseline (514.128 us; speedup 1.0000x reference)
//
#include <hip/hip_runtime.h>
#include <hip/hip_bf16.h>
#include <cstdint>
#include <cstddef>

typedef __bf16 bf16;
typedef __attribute__((ext_vector_type(8))) __bf16 bf16x8;
typedef __attribute__((ext_vector_type(4))) float f32x4;
typedef __attribute__((ext_vector_type(16))) float f32x16;

#define B_SZ  8192
#define NAGENT 8
#define NA_N  16
#define OBS_DD 2048
#define ACT_DD 128
#define IN_DD 2176
#define H1_D  1024
#define H2_D  1024

#define BM 256
#define BN 256
#define BK 64
#define GRID_M (B_SZ / BM)   // 32
#define GRID_N (1024 / BN)   // 4

__device__ __forceinline__ void gload16(const void* g, void* l) {
    __builtin_amdgcn_global_load_lds(
        (__attribute__((address_space(1))) void*)(g),
        (__attribute__((address_space(3))) void*)(l), 16, 0, 0);
}

#define MFMA32(a, b, c) __builtin_amdgcn_mfma_f32_32x32x16_bf16((a), (b), (c), 0, 0, 0)

// ---------- preprocessing (verified rounds 1-4) ----------

__global__ void k_convert_x(const float* __restrict__ obs,
                            const float* __restrict__ act,
                            bf16* __restrict__ xb) {
    const int chunks = IN_DD / 8;          // 272
    int idx = blockIdx.x * blockDim.x + threadIdx.x;
    if (idx >= B_SZ * chunks) return;
    int b = idx / chunks;
    int c8 = idx - b * chunks;
    const float* src = (c8 < OBS_DD / 8)
        ? (obs + (size_t)b * OBS_DD + c8 * 8)
        : (act + (size_t)b * ACT_DD + (c8 - OBS_DD / 8) * 8);
    float4 v0 = ((const float4*)src)[0];
    float4 v1 = ((const float4*)src)[1];
    bf16x8 o;
    o[0] = (bf16)v0.x; o[1] = (bf16)v0.y; o[2] = (bf16)v0.z; o[3] = (bf16)v0.w;
    o[4] = (bf16)v1.x; o[5] = (bf16)v1.y; o[6] = (bf16)v1.z; o[7] = (bf16)v1.w;
    ((bf16x8*)(xb + (size_t)b * IN_DD))[c8] = o;
}

__global__ void k_transpose_w(const float* __restrict__ src, bf16* __restrict__ dst,
                              int K, int H, int maskStart) {
    __shared__ float tile[32][33];
    int a = blockIdx.z;
    int k0 = blockIdx.x * 32, h0 = blockIdx.y * 32;
    const float* s = src + (size_t)a * K * H;
    bf16* d = dst + (size_t)a * K * H;
    int tx = threadIdx.x, ty = threadIdx.y;
    #pragma unroll
    for (int i = 0; i < 32; i += 8) {
        int k = k0 + ty + i;
        float v = s[(size_t)k * H + h0 + tx];
        if (k >= maskStart) {
            int g = k - maskStart;
            if ((g >> 4) == a) v = 0.f;
        }
        tile[ty + i][tx] = v;
    }
    __syncthreads();
    #pragma unroll
    for (int i = 0; i < 32; i += 8) {
        d[(size_t)(h0 + ty + i) * K + k0 + tx] = (bf16)tile[tx][ty + i];
    }
}

__global__ void k_transpose_w3(const float* __restrict__ src, bf16* __restrict__ dst) {
    int idx = blockIdx.x * blockDim.x + threadIdx.x;
    if (idx >= NAGENT * NA_N * H2_D) return;
    int a = idx / (NA_N * H2_D);
    int n = (idx / H2_D) % NA_N;
    int k = idx % H2_D;
    dst[idx] = (bf16)src[(size_t)a * H2_D * NA_N + (size_t)k * NA_N + n];
}

// out[b, a*16+n] = b3[a,n]  (bias pre-init; fused L3 atomically accumulates)
__global__ void k_init_out(const float* __restrict__ b3, float* __restrict__ out) {
    int i = blockIdx.x * blockDim.x + threadIdx.x;
    if (i < B_SZ * NAGENT * NA_N) out[i] = b3[i & 127];
}

// ---------- 256x256x64 8-phase GEMM, 32x32x16 MFMA engine ----------
// LDS slots (elems): A: (t&1)*16384 ; B: 32768 + (t&1)*16384. 128 KiB total.
// A(t+1) staged phases 0/1 (slot ^1). B(t+2) staged phase 3 (slot t&1, safe:
// issued after phase-2 barrier => all waves consumed B(t)). Boundary vmcnt(4)
// leaves exactly B(t+2) in flight. FUSE as before.
template<int FUSE>
__global__ __launch_bounds__(512, 2)
void k_gemm256(const bf16* __restrict__ Ain, size_t aStride, int lda,
               const bf16* __restrict__ Bw, const float* __restrict__ bias,
               bf16* __restrict__ Cout, size_t cStride, int K,
               int aOff, int gridZ,
               const bf16* __restrict__ W3Tp, float* __restrict__ outp) {
    extern __shared__ bf16 lds[];   // 65536 elems = 128 KiB

    const int tid = threadIdx.x;
    const int w = tid >> 6;
    const int l = tid & 63;

    // XCD-chunked remap (nwg = 128*gridZ, % 8 == 0)
    int flat = blockIdx.x + GRID_M * (blockIdx.y + GRID_N * blockIdx.z);
    int q8 = (GRID_M * GRID_N * gridZ) >> 3;
    int lin2 = (flat & 7) * q8 + (flat >> 3);
    const int mt = lin2 % GRID_M;
    int rest = lin2 / GRID_M;
    const int ntile = rest % GRID_N;
    const int az = rest / GRID_N;
    const int aw = az + aOff;

    const int rowBase = mt * BM;
    const int colBase = ntile * BN;
    const bf16* Aag = Ain + (size_t)az * aStride;
    const bf16* Bag = Bw + (size_t)aw * (size_t)1024 * K;

    const int wr = (w >> 2) * 128;   // wave rows (2M), 4 m-frags of 32
    const int wc = (w & 3) * 64;     // wave cols (4N), 2 n-frags of 32
    const int r31 = l & 31;
    const int hi = l >> 5;
    const int x7 = l & 7;

    // 32x32x16 fragment addressing: row = base + (l&31); k-chunk = ks*2 + hi,
    // phys chunk = logical ^ (row&7) = logical ^ (l&7). Row = 64 elems (128 B).
    const int arow = (wr + r31) * 64;            // + m*2048
    const int brow = (wc + r31) * 64;            // + n*2048
    int cs[4];
    #pragma unroll
    for (int ks = 0; ks < 4; ++ks) cs[ks] = ((ks * 2 + hi) ^ x7) * 8;

    // staging (round-3 verified): lane -> row w*16+(l>>3), pre-swizzled col
    const int sR = w * 16 + (l >> 3);
    const int sC = ((l & 7) ^ (l >> 3)) * 8;
    const bf16* pA0 = Aag + (size_t)(rowBase + sR) * lda + sC;
    const bf16* pA1 = Aag + (size_t)(rowBase + 128 + sR) * lda + sC;
    const bf16* pB0 = Bag + (size_t)(colBase + sR) * K + sC;
    const bf16* pB1 = Bag + (size_t)(colBase + 128 + sR) * K + sC;
    const size_t l8a = (size_t)8 * lda;
    const size_t l8b = (size_t)8 * K;

    const int nkt = K / BK;

#define STAGE_A(t1, half) do {                                              \
        const bf16* g_ = ((half) ? pA1 : pA0) + (t1) * BK;                  \
        bf16* d_ = &lds[(((t1) & 1) * 16384) + (half) * 8192 + w * 1024];   \
        gload16(g_, d_);                                                    \
        gload16(g_ + l8a, d_ + 512);                                        \
    } while (0)
#define STAGE_B(t2, half) do {                                              \
        const bf16* g_ = ((half) ? pB1 : pB0) + (t2) * BK;                  \
        bf16* d_ = &lds[32768 + (((t2) & 1) * 16384) + (half) * 8192 + w * 1024]; \
        gload16(g_, d_);                                                    \
        gload16(g_ + l8b, d_ + 512);                                        \
    } while (0)

    f32x16 acc[4][2] = {};
    bf16x8 a0, a1, a2, a3, b00, b01, b10, b11;

// 8 MFMAs: m-pair (M0,M1) x n(0,1) x ks-pair via (a0..a3 = A[M0,ksA],A[M0,ksB],A[M1,ksA],A[M1,ksB])
#define PH_MFMA(M0, M1)                                                     \
    do {                                                                    \
        acc[M0][0] = MFMA32(a0, b00, acc[M0][0]);                           \
        acc[M0][1] = MFMA32(a0, b10, acc[M0][1]);                           \
        acc[M1][0] = MFMA32(a2, b00, acc[M1][0]);                           \
        acc[M1][1] = MFMA32(a2, b10, acc[M1][1]);                           \
        acc[M0][0] = MFMA32(a1, b01, acc[M0][0]);                           \
        acc[M0][1] = MFMA32(a1, b11, acc[M0][1]);                           \
        acc[M1][0] = MFMA32(a3, b01, acc[M1][0]);                           \
        acc[M1][1] = MFMA32(a3, b11, acc[M1][1]);                           \
    } while (0)

    // prologue: A(0), B(0), B(1); wait tile-0 landed (B(1) stays in flight)
    STAGE_A(0, 0); STAGE_A(0, 1);
    STAGE_B(0, 0); STAGE_B(0, 1);
    if (nkt > 1) { STAGE_B(1, 0); STAGE_B(1, 1); }
    asm volatile("s_waitcnt vmcnt(4)" ::: "memory");
    __builtin_amdgcn_s_barrier();

    for (int t = 0; t < nkt; ++t) {
        const int aS = (t & 1) * 16384;
        const int bS = 32768 + (t & 1) * 16384;

        // ---- phase 0: A m0,m1 ks0,ks1 + B ks0,ks1; stage A(t+1)-lo; MFMA m0,m1
        a0 = *(const bf16x8*)&lds[aS + arow + 0 * 2048 + cs[0]];
        a1 = *(const bf16x8*)&lds[aS + arow + 0 * 2048 + cs[1]];
        a2 = *(const bf16x8*)&lds[aS + arow + 1 * 2048 + cs[0]];
        a3 = *(const bf16x8*)&lds[aS + arow + 1 * 2048 + cs[1]];
        b00 = *(const bf16x8*)&lds[bS + brow + 0 * 2048 + cs[0]];
        b01 = *(const bf16x8*)&lds[bS + brow + 0 * 2048 + cs[1]];
        b10 = *(const bf16x8*)&lds[bS + brow + 1 * 2048 + cs[0]];
        b11 = *(const bf16x8*)&lds[bS + brow + 1 * 2048 + cs[1]];
        if (t + 1 < nkt) STAGE_A(t + 1, 0);
        __builtin_amdgcn_s_barrier();
        __builtin_amdgcn_s_setprio(1);
        PH_MFMA(0, 1);
        __builtin_amdgcn_s_setprio(0);
        __builtin_amdgcn_s_barrier();

        // ---- phase 1: A m2,m3 ks0,ks1; stage A(t+1)-hi; MFMA m2,m3
        a0 = *(const bf16x8*)&lds[aS + arow + 2 * 2048 + cs[0]];
        a1 = *(const bf16x8*)&lds[aS + arow + 2 * 2048 + cs[1]];
        a2 = *(const bf16x8*)&lds[aS + arow + 3 * 2048 + cs[0]];
        a3 = *(const bf16x8*)&lds[aS + arow + 3 * 2048 + cs[1]];
        if (t + 1 < nkt) STAGE_A(t + 1, 1);
        __builtin_amdgcn_s_barrier();
        __builtin_amdgcn_s_setprio(1);
        PH_MFMA(2, 3);
        __builtin_amdgcn_s_setprio(0);
        __builtin_amdgcn_s_barrier();

        // ---- phase 2: A m0,m1 ks2,ks3 + B ks2,ks3; MFMA m0,m1
        a0 = *(const bf16x8*)&lds[aS + arow + 0 * 2048 + cs[2]];
        a1 = *(const bf16x8*)&lds[aS + arow + 0 * 2048 + cs[3]];
        a2 = *(const bf16x8*)&lds[aS + arow + 1 * 2048 + cs[2]];
        a3 = *(const bf16x8*)&lds[aS + arow + 1 * 2048 + cs[3]];
        b00 = *(const bf16x8*)&lds[bS + brow + 0 * 2048 + cs[2]];
        b01 = *(const bf16x8*)&lds[bS + brow + 0 * 2048 + cs[3]];
        b10 = *(const bf16x8*)&lds[bS + brow + 1 * 2048 + cs[2]];
        b11 = *(const bf16x8*)&lds[bS + brow + 1 * 2048 + cs[3]];
        __builtin_amdgcn_s_barrier();
        __builtin_amdgcn_s_setprio(1);
        PH_MFMA(0, 1);
        __builtin_amdgcn_s_setprio(0);
        __builtin_amdgcn_s_barrier();

        // ---- phase 3: A m2,m3 ks2,ks3; stage B(t+2) both halves (race-free:
        // after phase-2 barrier all waves consumed B(t)); MFMA; counted vmcnt
        a0 = *(const bf16x8*)&lds[aS + arow + 2 * 2048 + cs[2]];
        a1 = *(const bf16x8*)&lds[aS + arow + 2 * 2048 + cs[3]];
        a2 = *(const bf16x8*)&lds[aS + arow + 3 * 2048 + cs[2]];
        a3 = *(const bf16x8*)&lds[aS + arow + 3 * 2048 + cs[3]];
        if (t + 2 < nkt) { STAGE_B(t + 2, 0); STAGE_B(t + 2, 1); }
        __builtin_amdgcn_s_barrier();
        __builtin_amdgcn_s_setprio(1);
        PH_MFMA(2, 3);
        __builtin_amdgcn_s_setprio(0);
        if (t + 2 < nkt) {
            asm volatile("s_waitcnt vmcnt(4)" ::: "memory");   // B(t+2) stays in flight
        } else {
            asm volatile("s_waitcnt vmcnt(0)" ::: "memory");   // tail drain
        }
        __builtin_amdgcn_s_barrier();
    }
#undef STAGE_A
#undef STAGE_B
#undef PH_MFMA

    // ---- epilogue: bias + relu -> swizzled C-LDS tile [256][256] bf16
    __syncthreads();
    const float* bAg = bias + (size_t)aw * 1024;
    float bb2[2];
    #pragma unroll
    for (int n = 0; n < 2; ++n) bb2[n] = bAg[colBase + wc + n * 32 + r31];
    #pragma unroll
    for (int m = 0; m < 4; ++m)
        #pragma unroll
        for (int n = 0; n < 2; ++n)
            #pragma unroll
            for (int r = 0; r < 16; ++r) {
                float v = acc[m][n][r] + bb2[n];
                v = fmaxf(v, 0.f);
                int row = wr + m * 32 + (r & 3) + 8 * (r >> 2) + 4 * hi;
                int col = wc + n * 32 + r31;
                lds[row * 256 + ((((col >> 3) ^ (row & 7)) << 3) | (col & 7))] = (bf16)v;
            }
    __syncthreads();

    if constexpr (!FUSE) {
        bf16* Cg = Cout + (size_t)az * cStride + (size_t)rowBase * 1024 + colBase;
        const int er = tid >> 5;
        const int ec = tid & 31;
        #pragma unroll
        for (int i = 0; i < 16; ++i) {
            int row = i * 16 + er;
            int phys = ec ^ (row & 7);
            *(bf16x8*)&Cg[(size_t)row * 1024 + ec * 8] =
                *(const bf16x8*)&lds[row * 256 + phys * 8];
        }
    } else {
        // fused L3: h2 tile (256 rows, k-slice [colBase,colBase+256)) x W3T[aw]
        const bf16* w3a = W3Tp + (size_t)aw * NA_N * H2_D;
        f32x4 oacc[2] = {};
        const int lr = l & 15, lq = l >> 4;
        const int frow0 = w * 32;
        #pragma unroll
        for (int ks = 0; ks < 8; ++ks) {
            bf16x8 bfrag = *(const bf16x8*)&w3a[(size_t)lr * H2_D + colBase + ks * 32 + lq * 8];
            #pragma unroll
            for (int mm = 0; mm < 2; ++mm) {
                int row = frow0 + mm * 16 + lr;
                int lc = (ks * 4 + lq) ^ (row & 7);
                bf16x8 afrag = *(const bf16x8*)&lds[row * 256 + lc * 8];
                oacc[mm] = __builtin_amdgcn_mfma_f32_16x16x32_bf16(afrag, bfrag, oacc[mm], 0, 0, 0);
            }
        }
        #pragma unroll
        for (int mm = 0; mm < 2; ++mm)
            #pragma unroll
            for (int r = 0; r < 4; ++r)
                atomicAdd(&outp[(size_t)(rowBase + frow0 + mm * 16 + lq * 4 + r) * 128
                                + aw * NA_N + lr], oacc[mm][r]);
    }
}

// ---------- launcher ----------
extern "C" void kernel_launch(void* const* d_in, const int* in_sizes, int n_in,
                              void* d_out, int out_size, void* d_ws, size_t ws_size,
                              hipStream_t stream) {
    const float* obs = (const float*)d_in[0];
    const float* act = (const float*)d_in[1];
    const float* W1 = (const float*)d_in[2];
    const float* b1 = (const float*)d_in[3];
    const float* W2 = (const float*)d_in[4];
    const float* b2 = (const float*)d_in[5];
    const float* W3 = (const float*)d_in[6];
    const float* b3 = (const float*)d_in[7];
    float* out = (float*)d_out;

    const size_t SZ_XB  = (size_t)B_SZ * IN_DD * 2;
    const size_t SZ_W1T = (size_t)NAGENT * H1_D * IN_DD * 2;
    const size_t SZ_W2T = (size_t)NAGENT * H1_D * H2_D * 2;
    const size_t SZ_W3T = (size_t)NAGENT * NA_N * H2_D * 2;
    const size_t SZ_H1  = (size_t)B_SZ * H1_D * 2;
    const size_t SZ_FIX = SZ_XB + SZ_W1T + SZ_W2T + SZ_W3T;

    char* ws = (char*)d_ws;
    bf16* Xb  = (bf16*)ws;
    bf16* W1T = (bf16*)(ws + SZ_XB);
    bf16* W2T = (bf16*)(ws + SZ_XB + SZ_W1T);
    bf16* W3T = (bf16*)(ws + SZ_XB + SZ_W1T + SZ_W2T);
    char* hbase = ws + SZ_FIX;

    // largest G (agents per pass) that fits: h1 only (h2/L3 fused)
    int G = 8;
    while (G > 1 && ws_size < SZ_FIX + (size_t)G * SZ_H1) G >>= 1;

    (void)hipFuncSetAttribute((const void*)k_gemm256<0>,
                              hipFuncAttributeMaxDynamicSharedMemorySize, 131072);
    (void)hipFuncSetAttribute((const void*)k_gemm256<1>,
                              hipFuncAttributeMaxDynamicSharedMemorySize, 131072);

    // out = b3 broadcast (fused L3 accumulates on top)
    k_init_out<<<(B_SZ * 128 + 255) / 256, 256, 0, stream>>>(b3, out);

    // preprocessing
    {
        int n = B_SZ * (IN_DD / 8);
        k_convert_x<<<(n + 255) / 256, 256, 0, stream>>>(obs, act, Xb);
    }
    k_transpose_w<<<dim3(IN_DD / 32, H1_D / 32, NAGENT), dim3(32, 8), 0, stream>>>(
        W1, W1T, IN_DD, H1_D, OBS_DD);
    k_transpose_w<<<dim3(H1_D / 32, H2_D / 32, NAGENT), dim3(32, 8), 0, stream>>>(
        W2, W2T, H1_D, H2_D, 1 << 30);
    {
        int n = NAGENT * NA_N * H2_D;
        k_transpose_w3<<<(n + 255) / 256, 256, 0, stream>>>(W3, W3T);
    }

    const size_t agElems = (size_t)B_SZ * H1_D;
    bf16* h1 = (bf16*)hbase;

    for (int g0 = 0; g0 < NAGENT; g0 += G) {
        k_gemm256<0><<<dim3(GRID_M, GRID_N, G), 512, 131072, stream>>>(
            Xb, 0, IN_DD, W1T, b1, h1, agElems, IN_DD, g0, G, nullptr, nullptr);
        k_gemm256<1><<<dim3(GRID_M, GRID_N, G), 512, 131072, stream>>>(
            h1, agElems, H1_D, W2T, b2, nullptr, 0, H1_D, g0, G, W3T, out);
    }
    (void)in_sizes; (void)n_in; (void)out_size;
}

// Round 6
// 454.198 us; speedup vs baseline: 1.1319x; 1.1319x over previous
//
#include <hip/hip_runtime.h>
#include <hip/hip_bf16.h>
#include <cstdint>
#include <cstddef>

typedef __bf16 bf16;
typedef __attribute__((ext_vector_type(8))) __bf16 bf16x8;
typedef __attribute__((ext_vector_type(4))) float f32x4;
typedef __attribute__((ext_vector_type(4))) int i32x4;
typedef __attribute__((address_space(3))) const bf16* lds_cp;

#define B_SZ  8192
#define NAGENT 8
#define NA_N  16
#define OBS_DD 2048
#define ACT_DD 128
#define IN_DD 2176
#define H1_D  1024
#define H2_D  1024

#define BM 256
#define BN 256
#define BK 64
#define GRID_M (B_SZ / BM)   // 32
#define GRID_N (1024 / BN)   // 4

__device__ __forceinline__ void gload16(const void* g, void* l) {
    __builtin_amdgcn_global_load_lds(
        (__attribute__((address_space(1))) void*)(g),
        (__attribute__((address_space(3))) void*)(l), 16, 0, 0);
}

// ---------- preprocessing (verified rounds 1-5) ----------

__global__ void k_convert_x(const float* __restrict__ obs,
                            const float* __restrict__ act,
                            bf16* __restrict__ xb) {
    const int chunks = IN_DD / 8;          // 272
    int idx = blockIdx.x * blockDim.x + threadIdx.x;
    if (idx >= B_SZ * chunks) return;
    int b = idx / chunks;
    int c8 = idx - b * chunks;
    const float* src = (c8 < OBS_DD / 8)
        ? (obs + (size_t)b * OBS_DD + c8 * 8)
        : (act + (size_t)b * ACT_DD + (c8 - OBS_DD / 8) * 8);
    float4 v0 = ((const float4*)src)[0];
    float4 v1 = ((const float4*)src)[1];
    bf16x8 o;
    o[0] = (bf16)v0.x; o[1] = (bf16)v0.y; o[2] = (bf16)v0.z; o[3] = (bf16)v0.w;
    o[4] = (bf16)v1.x; o[5] = (bf16)v1.y; o[6] = (bf16)v1.z; o[7] = (bf16)v1.w;
    ((bf16x8*)(xb + (size_t)b * IN_DD))[c8] = o;
}

__global__ void k_transpose_w(const float* __restrict__ src, bf16* __restrict__ dst,
                              int K, int H, int maskStart) {
    __shared__ float tile[32][33];
    int a = blockIdx.z;
    int k0 = blockIdx.x * 32, h0 = blockIdx.y * 32;
    const float* s = src + (size_t)a * K * H;
    bf16* d = dst + (size_t)a * K * H;
    int tx = threadIdx.x, ty = threadIdx.y;
    #pragma unroll
    for (int i = 0; i < 32; i += 8) {
        int k = k0 + ty + i;
        float v = s[(size_t)k * H + h0 + tx];
        if (k >= maskStart) {
            int g = k - maskStart;
            if ((g >> 4) == a) v = 0.f;
        }
        tile[ty + i][tx] = v;
    }
    __syncthreads();
    #pragma unroll
    for (int i = 0; i < 32; i += 8) {
        d[(size_t)(h0 + ty + i) * K + k0 + tx] = (bf16)tile[tx][ty + i];
    }
}

__global__ void k_transpose_w3(const float* __restrict__ src, bf16* __restrict__ dst) {
    int idx = blockIdx.x * blockDim.x + threadIdx.x;
    if (idx >= NAGENT * NA_N * H2_D) return;
    int a = idx / (NA_N * H2_D);
    int n = (idx / H2_D) % NA_N;
    int k = idx % H2_D;
    dst[idx] = (bf16)src[(size_t)a * H2_D * NA_N + (size_t)k * NA_N + n];
}

// out[b, a*16+n] = b3[a,n]  (bias pre-init; fused L3 atomically accumulates)
__global__ void k_init_out(const float* __restrict__ b3, float* __restrict__ out) {
    int i = blockIdx.x * blockDim.x + threadIdx.x;
    if (i < B_SZ * NAGENT * NA_N) out[i] = b3[i & 127];
}

// ---------- 256x256x64 GEMM: 1 barrier/K-tile, counted-lgkmcnt interleave ----------
// Slots (elems): A: (t&1)*16384 ; B: 32768 + (t&1)*16384. 128 KiB total.
// Tile t body: stage A(t+1),B(t+1) early; 4 read-groups (asm ds_read_b128)
// interleaved with 4x16 MFMA clusters via lgkmcnt(8/4/4/0)+sched_barrier;
// vmcnt(0)+s_barrier at tile end (stages landed during body => free).
// Correctness: reads(t) all complete before each wave's last lgkm wait; the
// single barrier then orders them before stage(t+2) overwrites slot t&1.
#define DSR4(d0, d1, d2, d3, addr, O0, O1, O2, O3)                      \
    asm volatile("ds_read_b128 %0, %4 offset:" #O0 "\n\t"               \
                 "ds_read_b128 %1, %4 offset:" #O1 "\n\t"               \
                 "ds_read_b128 %2, %4 offset:" #O2 "\n\t"               \
                 "ds_read_b128 %3, %4 offset:" #O3                      \
                 : "=&v"(d0), "=&v"(d1), "=&v"(d2), "=&v"(d3)           \
                 : "v"(addr))

#define BC(x) __builtin_bit_cast(bf16x8, x)

template<int FUSE>
__global__ __launch_bounds__(512, 1)
void k_gemm256(const bf16* __restrict__ Ain, size_t aStride, int lda,
               const bf16* __restrict__ Bw, const float* __restrict__ bias,
               bf16* __restrict__ Cout, size_t cStride, int K,
               int aOff, int gridZ,
               const bf16* __restrict__ W3Tp, float* __restrict__ outp) {
    extern __shared__ bf16 lds[];   // 65536 elems = 128 KiB

    const int tid = threadIdx.x;
    const int w = tid >> 6;
    const int l = tid & 63;

    // XCD-chunked remap (nwg = 128*gridZ, % 8 == 0)
    int flat = blockIdx.x + GRID_M * (blockIdx.y + GRID_N * blockIdx.z);
    int q8 = (GRID_M * GRID_N * gridZ) >> 3;
    int lin2 = (flat & 7) * q8 + (flat >> 3);
    const int mt = lin2 % GRID_M;
    int rest = lin2 / GRID_M;
    const int ntile = rest % GRID_N;
    const int az = rest / GRID_N;
    const int aw = az + aOff;

    const int rowBase = mt * BM;
    const int colBase = ntile * BN;
    const bf16* Aag = Ain + (size_t)az * aStride;
    const bf16* Bag = Bw + (size_t)aw * (size_t)1024 * K;

    const int wr = (w >> 2) * 128;   // wave rows (2M)
    const int wc = (w & 3) * 64;     // wave cols (4N)
    const int lr = l & 15;
    const int lq = l >> 4;

    // fragment addressing (r3-verified): chunk swizzle phys = logical ^ (row & 7)
    const int rowA = (wr + lr) * BK;
    const int rowB = (wc + lr) * BK;
    const int ck0 = ((lq ^ (lr & 7)) * 8);
    const int ck1 = (((4 + lq) ^ (lr & 7)) * 8);

    // staging (r3-verified): lane -> row w*16+(l>>3), pre-swizzled col
    const int sRow = w * 16 + (l >> 3);
    const int sCol = ((l & 7) ^ (l >> 3)) * 8;
    const bf16* pA0 = Aag + (size_t)(rowBase + sRow) * lda + sCol;
    const bf16* pA1 = Aag + (size_t)(rowBase + 128 + sRow) * lda + sCol;
    const bf16* pB0 = Bag + (size_t)(colBase + sRow) * K + sCol;
    const bf16* pB1 = Bag + (size_t)(colBase + 128 + sRow) * K + sCol;
    const size_t l8a = (size_t)8 * lda;
    const size_t l8b = (size_t)8 * K;

    const int nkt = K / BK;

#define STAGE_A(t1, half) do {                                              \
        const bf16* g_ = ((half) ? pA1 : pA0) + (t1) * BK;                  \
        bf16* d_ = &lds[(((t1) & 1) * 16384) + (half) * 8192 + w * 1024];   \
        gload16(g_, d_);                                                    \
        gload16(g_ + l8a, d_ + 512);                                        \
    } while (0)
#define STAGE_B(t2, half) do {                                              \
        const bf16* g_ = ((half) ? pB1 : pB0) + (t2) * BK;                  \
        bf16* d_ = &lds[32768 + (((t2) & 1) * 16384) + (half) * 8192 + w * 1024]; \
        gload16(g_, d_);                                                    \
        gload16(g_ + l8b, d_ + 512);                                        \
    } while (0)

    f32x4 acc[8][4] = {};
    i32x4 ra0, ra1, ra2, ra3;   // A m0-3 ks0
    i32x4 rb0, rb1, rb2, rb3;   // B ks0
    i32x4 rc0, rc1, rc2, rc3;   // A m4-7 ks0
    i32x4 rd0, rd1, rd2, rd3;   // B ks1
    i32x4 re0, re1, re2, re3;   // A m0-3 ks1
    i32x4 rf0, rf1, rf2, rf3;   // A m4-7 ks1

#define MFMA16(ACC0, A0, A1, A2, A3, B0, B1, B2, B3)                        \
    do {                                                                    \
        acc[ACC0+0][0] = __builtin_amdgcn_mfma_f32_16x16x32_bf16(BC(A0), BC(B0), acc[ACC0+0][0], 0, 0, 0); \
        acc[ACC0+1][0] = __builtin_amdgcn_mfma_f32_16x16x32_bf16(BC(A1), BC(B0), acc[ACC0+1][0], 0, 0, 0); \
        acc[ACC0+2][0] = __builtin_amdgcn_mfma_f32_16x16x32_bf16(BC(A2), BC(B0), acc[ACC0+2][0], 0, 0, 0); \
        acc[ACC0+3][0] = __builtin_amdgcn_mfma_f32_16x16x32_bf16(BC(A3), BC(B0), acc[ACC0+3][0], 0, 0, 0); \
        acc[ACC0+0][1] = __builtin_amdgcn_mfma_f32_16x16x32_bf16(BC(A0), BC(B1), acc[ACC0+0][1], 0, 0, 0); \
        acc[ACC0+1][1] = __builtin_amdgcn_mfma_f32_16x16x32_bf16(BC(A1), BC(B1), acc[ACC0+1][1], 0, 0, 0); \
        acc[ACC0+2][1] = __builtin_amdgcn_mfma_f32_16x16x32_bf16(BC(A2), BC(B1), acc[ACC0+2][1], 0, 0, 0); \
        acc[ACC0+3][1] = __builtin_amdgcn_mfma_f32_16x16x32_bf16(BC(A3), BC(B1), acc[ACC0+3][1], 0, 0, 0); \
        acc[ACC0+0][2] = __builtin_amdgcn_mfma_f32_16x16x32_bf16(BC(A0), BC(B2), acc[ACC0+0][2], 0, 0, 0); \
        acc[ACC0+1][2] = __builtin_amdgcn_mfma_f32_16x16x32_bf16(BC(A1), BC(B2), acc[ACC0+1][2], 0, 0, 0); \
        acc[ACC0+2][2] = __builtin_amdgcn_mfma_f32_16x16x32_bf16(BC(A2), BC(B2), acc[ACC0+2][2], 0, 0, 0); \
        acc[ACC0+3][2] = __builtin_amdgcn_mfma_f32_16x16x32_bf16(BC(A3), BC(B2), acc[ACC0+3][2], 0, 0, 0); \
        acc[ACC0+0][3] = __builtin_amdgcn_mfma_f32_16x16x32_bf16(BC(A0), BC(B3), acc[ACC0+0][3], 0, 0, 0); \
        acc[ACC0+1][3] = __builtin_amdgcn_mfma_f32_16x16x32_bf16(BC(A1), BC(B3), acc[ACC0+1][3], 0, 0, 0); \
        acc[ACC0+2][3] = __builtin_amdgcn_mfma_f32_16x16x32_bf16(BC(A2), BC(B3), acc[ACC0+2][3], 0, 0, 0); \
        acc[ACC0+3][3] = __builtin_amdgcn_mfma_f32_16x16x32_bf16(BC(A3), BC(B3), acc[ACC0+3][3], 0, 0, 0); \
    } while (0)

    // prologue: stage tile 0, drain, barrier
    STAGE_A(0, 0); STAGE_A(0, 1);
    STAGE_B(0, 0); STAGE_B(0, 1);
    asm volatile("s_waitcnt vmcnt(0)" ::: "memory");
    __builtin_amdgcn_s_barrier();

    for (int t = 0; t < nkt; ++t) {
        const int dbuf = (t & 1) * 16384;
        lds_cp adrA0 = (lds_cp)lds + (dbuf + rowA + ck0);
        lds_cp adrA1 = (lds_cp)lds + (dbuf + rowA + ck1);
        lds_cp adrB0 = (lds_cp)lds + (32768 + dbuf + rowB + ck0);
        lds_cp adrB1 = (lds_cp)lds + (32768 + dbuf + rowB + ck1);

        // stage next tile early: lands during this tile's ~2000-cy body
        if (t + 1 < nkt) {
            STAGE_A(t + 1, 0); STAGE_A(t + 1, 1);
            STAGE_B(t + 1, 0); STAGE_B(t + 1, 1);
        }

        // read groups 1+2 (16 ds_read_b128)
        DSR4(ra0, ra1, ra2, ra3, adrA0, 0, 2048, 4096, 6144);
        DSR4(rb0, rb1, rb2, rb3, adrB0, 0, 2048, 4096, 6144);
        DSR4(rc0, rc1, rc2, rc3, adrA0, 8192, 10240, 12288, 14336);
        DSR4(rd0, rd1, rd2, rd3, adrB1, 0, 2048, 4096, 6144);

        asm volatile("s_waitcnt lgkmcnt(8)" ::: "memory");   // group 1 done
        __builtin_amdgcn_sched_barrier(0);
        __builtin_amdgcn_s_setprio(1);
        MFMA16(0, ra0, ra1, ra2, ra3, rb0, rb1, rb2, rb3);   // m0-3 ks0
        __builtin_amdgcn_s_setprio(0);

        DSR4(re0, re1, re2, re3, adrA1, 0, 2048, 4096, 6144); // group 3
        asm volatile("s_waitcnt lgkmcnt(4)" ::: "memory");   // group 2 done
        __builtin_amdgcn_sched_barrier(0);
        __builtin_amdgcn_s_setprio(1);
        MFMA16(4, rc0, rc1, rc2, rc3, rb0, rb1, rb2, rb3);   // m4-7 ks0
        __builtin_amdgcn_s_setprio(0);

        DSR4(rf0, rf1, rf2, rf3, adrA1, 8192, 10240, 12288, 14336); // group 4
        asm volatile("s_waitcnt lgkmcnt(4)" ::: "memory");   // group 3 done
        __builtin_amdgcn_sched_barrier(0);
        __builtin_amdgcn_s_setprio(1);
        MFMA16(0, re0, re1, re2, re3, rd0, rd1, rd2, rd3);   // m0-3 ks1
        __builtin_amdgcn_s_setprio(0);

        asm volatile("s_waitcnt lgkmcnt(0)" ::: "memory");   // group 4 done
        __builtin_amdgcn_sched_barrier(0);
        __builtin_amdgcn_s_setprio(1);
        MFMA16(4, rf0, rf1, rf2, rf3, rd0, rd1, rd2, rd3);   // m4-7 ks1
        __builtin_amdgcn_s_setprio(0);

        // tile end: next-tile stages landed (issued ~body-length ago); barrier
        // orders all waves' reads(t) before stage(t+2) reuses this slot.
        asm volatile("s_waitcnt vmcnt(0)" ::: "memory");
        __builtin_amdgcn_s_barrier();
    }
#undef STAGE_A
#undef STAGE_B
#undef MFMA16

    // ---- epilogue: bias + relu -> swizzled C-LDS tile [256][256] bf16 (r3-verified)
    __syncthreads();
    const float* bAg = bias + (size_t)aw * 1024;
    float bb4[4];
    #pragma unroll
    for (int n = 0; n < 4; ++n) bb4[n] = bAg[colBase + wc + n * 16 + lr];
    #pragma unroll
    for (int m = 0; m < 8; ++m)
        #pragma unroll
        for (int n = 0; n < 4; ++n)
            #pragma unroll
            for (int r = 0; r < 4; ++r) {
                float v = acc[m][n][r] + bb4[n];
                v = fmaxf(v, 0.f);
                int row = wr + m * 16 + lq * 4 + r;
                int col = wc + n * 16 + lr;
                lds[row * 256 + ((((col >> 3) ^ (row & 7)) << 3) | (col & 7))] = (bf16)v;
            }
    __syncthreads();

    if constexpr (!FUSE) {
        bf16* Cg = Cout + (size_t)az * cStride + (size_t)rowBase * 1024 + colBase;
        const int er = tid >> 5;
        const int ec = tid & 31;
        #pragma unroll
        for (int i = 0; i < 16; ++i) {
            int row = i * 16 + er;
            int phys = ec ^ (row & 7);
            *(bf16x8*)&Cg[(size_t)row * 1024 + ec * 8] =
                *(const bf16x8*)&lds[row * 256 + phys * 8];
        }
    } else {
        // fused L3: h2 tile (256 rows, k-slice [colBase,colBase+256)) x W3T[aw]
        const bf16* w3a = W3Tp + (size_t)aw * NA_N * H2_D;
        f32x4 oacc[2] = {};
        const int frow0 = w * 32;
        #pragma unroll
        for (int ks = 0; ks < 8; ++ks) {
            bf16x8 bfrag = *(const bf16x8*)&w3a[(size_t)lr * H2_D + colBase + ks * 32 + lq * 8];
            #pragma unroll
            for (int mm = 0; mm < 2; ++mm) {
                int row = frow0 + mm * 16 + lr;
                int lc = (ks * 4 + lq) ^ (row & 7);
                bf16x8 afrag = *(const bf16x8*)&lds[row * 256 + lc * 8];
                oacc[mm] = __builtin_amdgcn_mfma_f32_16x16x32_bf16(afrag, bfrag, oacc[mm], 0, 0, 0);
            }
        }
        #pragma unroll
        for (int mm = 0; mm < 2; ++mm)
            #pragma unroll
            for (int r = 0; r < 4; ++r)
                atomicAdd(&outp[(size_t)(rowBase + frow0 + mm * 16 + lq * 4 + r) * 128
                                + aw * NA_N + lr], oacc[mm][r]);
    }
}

// ---------- launcher ----------
extern "C" void kernel_launch(void* const* d_in, const int* in_sizes, int n_in,
                              void* d_out, int out_size, void* d_ws, size_t ws_size,
                              hipStream_t stream) {
    const float* obs = (const float*)d_in[0];
    const float* act = (const float*)d_in[1];
    const float* W1 = (const float*)d_in[2];
    const float* b1 = (const float*)d_in[3];
    const float* W2 = (const float*)d_in[4];
    const float* b2 = (const float*)d_in[5];
    const float* W3 = (const float*)d_in[6];
    const float* b3 = (const float*)d_in[7];
    float* out = (float*)d_out;

    const size_t SZ_XB  = (size_t)B_SZ * IN_DD * 2;
    const size_t SZ_W1T = (size_t)NAGENT * H1_D * IN_DD * 2;
    const size_t SZ_W2T = (size_t)NAGENT * H1_D * H2_D * 2;
    const size_t SZ_W3T = (size_t)NAGENT * NA_N * H2_D * 2;
    const size_t SZ_H1  = (size_t)B_SZ * H1_D * 2;
    const size_t SZ_FIX = SZ_XB + SZ_W1T + SZ_W2T + SZ_W3T;

    char* ws = (char*)d_ws;
    bf16* Xb  = (bf16*)ws;
    bf16* W1T = (bf16*)(ws + SZ_XB);
    bf16* W2T = (bf16*)(ws + SZ_XB + SZ_W1T);
    bf16* W3T = (bf16*)(ws + SZ_XB + SZ_W1T + SZ_W2T);
    char* hbase = ws + SZ_FIX;

    // largest G (agents per pass) that fits: h1 only (h2/L3 fused)
    int G = 8;
    while (G > 1 && ws_size < SZ_FIX + (size_t)G * SZ_H1) G >>= 1;

    (void)hipFuncSetAttribute((const void*)k_gemm256<0>,
                              hipFuncAttributeMaxDynamicSharedMemorySize, 131072);
    (void)hipFuncSetAttribute((const void*)k_gemm256<1>,
                              hipFuncAttributeMaxDynamicSharedMemorySize, 131072);

    // out = b3 broadcast (fused L3 accumulates on top)
    k_init_out<<<(B_SZ * 128 + 255) / 256, 256, 0, stream>>>(b3, out);

    // preprocessing
    {
        int n = B_SZ * (IN_DD / 8);
        k_convert_x<<<(n + 255) / 256, 256, 0, stream>>>(obs, act, Xb);
    }
    k_transpose_w<<<dim3(IN_DD / 32, H1_D / 32, NAGENT), dim3(32, 8), 0, stream>>>(
        W1, W1T, IN_DD, H1_D, OBS_DD);
    k_transpose_w<<<dim3(H1_D / 32, H2_D / 32, NAGENT), dim3(32, 8), 0, stream>>>(
        W2, W2T, H1_D, H2_D, 1 << 30);
    {
        int n = NAGENT * NA_N * H2_D;
        k_transpose_w3<<<(n + 255) / 256, 256, 0, stream>>>(W3, W3T);
    }

    const size_t agElems = (size_t)B_SZ * H1_D;
    bf16* h1 = (bf16*)hbase;

    for (int g0 = 0; g0 < NAGENT; g0 += G) {
        k_gemm256<0><<<dim3(GRID_M, GRID_N, G), 512, 131072, stream>>>(
            Xb, 0, IN_DD, W1T, b1, h1, agElems, IN_DD, g0, G, nullptr, nullptr);
        k_gemm256<1><<<dim3(GRID_M, GRID_N, G), 512, 131072, stream>>>(
            h1, agElems, H1_D, W2T, b2, nullptr, 0, H1_D, g0, G, W3T, out);
    }
    (void)in_sizes; (void)n_in; (void)out_size;
}